// Round 1
// baseline (508.177 us; speedup 1.0000x reference)
//
#include <hip/hip_runtime.h>
#include <math.h>

// AdaBoost fused inference:
//   logits = x @ W^T + b           [N=131072, E=256], F=512
//   pred   = round(sigmoid(logits)) == (logit > 0)  (fp32 half-even edge handled via tau band)
//   out    = sign( sum_e trunc(alpha_e) * pred_e )
//
// Only columns with trunc(alpha_e) != 0 contribute (~32% of 256). Each block
// compacts those columns (deterministic ballot prefix-sum), then runs a
// register-tiled fp32 GEMM over 128 rows x (active cols), with an exact fp64
// recompute for borderline logits |l| < TAU so sign decisions match the
// reference despite fp32 summation-order noise.

#define BM 128
#define BN 128
#define BK 16
#define TAU 2e-4f
#define F_DIM 512

__device__ __attribute__((noinline)) bool exact_pred(const float* __restrict__ xr,
                                                     const float* __restrict__ wr,
                                                     float bv) {
    double s = (double)bv;
    for (int k = 0; k < F_DIM; ++k)
        s = fma((double)xr[k], (double)wr[k], s);
    return s > 0.0;
}

__global__ __launch_bounds__(256)
void ada_fused(const float* __restrict__ x, const float* __restrict__ W,
               const float* __restrict__ bias, const float* __restrict__ alphas,
               float* __restrict__ out) {
    __shared__ float xs[BK][BM];    // x tile, transposed: xs[kk][row]
    __shared__ float wsh[BK][BN];   // W tile, transposed: wsh[kk][col]
    __shared__ int   rowacc[BM];
    __shared__ int   se[256];       // compacted estimator index
    __shared__ float st[256];       // trunc(alpha) for compacted estimator
    __shared__ float sb[256];       // bias for compacted estimator
    __shared__ int   wcnt[4];

    const int tid = threadIdx.x;
    const int n0  = blockIdx.x * BM;

    // ---- init compaction arrays (padded slots stay t=0 -> contribute nothing)
    se[tid] = 0; st[tid] = 0.0f; sb[tid] = 0.0f;
    if (tid < BM) rowacc[tid] = 0;
    __syncthreads();

    // ---- deterministic in-block compaction of columns with trunc(alpha)!=0
    const float t = truncf(alphas[tid]);
    const bool flag = (t != 0.0f);
    const unsigned long long mask = __ballot(flag);
    const int lane = tid & 63, wv = tid >> 6;
    if (lane == 0) wcnt[wv] = __popcll(mask);
    __syncthreads();
    int off = 0;
    #pragma unroll
    for (int w = 0; w < 4; ++w)
        if (w < wv) off += wcnt[w];
    const int M = wcnt[0] + wcnt[1] + wcnt[2] + wcnt[3];
    if (flag) {
        const int slot = off + __popcll(mask & ((1ull << lane) - 1ull));
        se[slot] = tid;
        st[slot] = t;
        sb[slot] = bias[tid];
    }
    __syncthreads();

    // ---- micro-tile mapping: 16x16 thread grid, each thread 8 rows x 8 cols
    const int ttx = tid & 15, tty = tid >> 4;
    const int row0 = ttx * 8, col0 = tty * 8;
    // staging mapping: each thread loads 8 consecutive floats of one row
    const int lr = tid >> 1;            // 0..127: tile row (x) / tile col (W)
    const int lk = (tid & 1) * 8;       // 0 or 8 within the BK=16 chunk

    for (int cb = 0; cb < M; cb += BN) {
        const bool active = (cb + col0) < M;   // this thread's cols exist
        const int serow = se[cb + lr];
        const float4* xp = (const float4*)(x + (size_t)(n0 + lr) * F_DIM + lk);
        const float4* wp = (const float4*)(W + (size_t)serow * F_DIM + lk);

        float acc[8][8];
        #pragma unroll
        for (int r = 0; r < 8; ++r)
            #pragma unroll
            for (int c = 0; c < 8; ++c) acc[r][c] = 0.0f;

        for (int k0 = 0; k0 < F_DIM; k0 += BK) {
            const float4 xa = xp[0], xb = xp[1];
            const float4 wa = wp[0], wb = wp[1];
            xp += BK / 4; wp += BK / 4;
            __syncthreads();   // previous compute done before overwrite
            xs[lk + 0][lr] = xa.x; xs[lk + 1][lr] = xa.y;
            xs[lk + 2][lr] = xa.z; xs[lk + 3][lr] = xa.w;
            xs[lk + 4][lr] = xb.x; xs[lk + 5][lr] = xb.y;
            xs[lk + 6][lr] = xb.z; xs[lk + 7][lr] = xb.w;
            wsh[lk + 0][lr] = wa.x; wsh[lk + 1][lr] = wa.y;
            wsh[lk + 2][lr] = wa.z; wsh[lk + 3][lr] = wa.w;
            wsh[lk + 4][lr] = wb.x; wsh[lk + 5][lr] = wb.y;
            wsh[lk + 6][lr] = wb.z; wsh[lk + 7][lr] = wb.w;
            __syncthreads();
            if (active) {
                #pragma unroll
                for (int kk = 0; kk < BK; ++kk) {
                    float a[8], w8[8];
                    *(float4*)&a[0]  = *(const float4*)&xs[kk][row0];
                    *(float4*)&a[4]  = *(const float4*)&xs[kk][row0 + 4];
                    *(float4*)&w8[0] = *(const float4*)&wsh[kk][col0];
                    *(float4*)&w8[4] = *(const float4*)&wsh[kk][col0 + 4];
                    #pragma unroll
                    for (int r = 0; r < 8; ++r)
                        #pragma unroll
                        for (int c = 0; c < 8; ++c)
                            acc[r][c] = fmaf(a[r], w8[c], acc[r][c]);
                }
            }
        }

        // ---- epilogue: threshold + integer-weighted count per row
        if (active) {
            int partial[8];
            #pragma unroll
            for (int r = 0; r < 8; ++r) partial[r] = 0;
            #pragma unroll
            for (int c = 0; c < 8; ++c) {
                const int j = cb + col0 + c;
                const float tv = st[j];
                if (tv != 0.0f) {           // padded/dead cols contribute 0
                    const float bv = sb[j];
                    const int e = se[j];
                    #pragma unroll
                    for (int r = 0; r < 8; ++r) {
                        const float logit = acc[r][c] + bv;
                        bool pred = (logit > 0.0f);
                        if (fabsf(logit) < TAU) {
                            // borderline: exact fp64 dot decides the sign
                            pred = exact_pred(x + (size_t)(n0 + row0 + r) * F_DIM,
                                              W + (size_t)e * F_DIM, bv);
                        }
                        if (pred) partial[r] += (int)tv;
                    }
                }
            }
            #pragma unroll
            for (int r = 0; r < 8; ++r)
                if (partial[r] != 0) atomicAdd(&rowacc[row0 + r], partial[r]);
        }
    }

    __syncthreads();
    if (tid < BM) {
        const int a = rowacc[tid];
        out[n0 + tid] = (a > 0) ? 1.0f : (a < 0 ? -1.0f : 0.0f);
    }
}

extern "C" void kernel_launch(void* const* d_in, const int* in_sizes, int n_in,
                              void* d_out, int out_size, void* d_ws, size_t ws_size,
                              hipStream_t stream) {
    const float* x      = (const float*)d_in[0];   // [N, 512]
    const float* W      = (const float*)d_in[1];   // [256, 512]
    const float* bias   = (const float*)d_in[2];   // [256]
    const float* alphas = (const float*)d_in[3];   // [256]
    float* out = (float*)d_out;                    // [N]

    const int n = in_sizes[0] / F_DIM;             // 131072
    const int nblocks = n / BM;                    // 1024 (N is a multiple of 128)

    ada_fused<<<dim3(nblocks), dim3(256), 0, stream>>>(x, W, bias, alphas, out);
}

// Round 2
// 495.229 us; speedup vs baseline: 1.0261x; 1.0261x over previous
//
#include <hip/hip_runtime.h>
#include <math.h>

// AdaBoost fused inference via bf16-split MFMA:
//   logits = x @ W^T + b   [N=131072, E=256], F=512; pred = (logit > 0)
//   out = sign( sum_e trunc(alpha_e) * pred_e ), only cols with trunc(alpha)!=0 matter.
//
// fp32 -> bf16 two-term split (RNE): x = xh + xl, W = wh + wl.
// logit ~= xh*wh + xl*wh + xh*wl  (drop xl*wl; total error bound ~2e-4 << TAU).
// Borderline logits |l| < TAU re-decided with an exact fp64 dot (matches np ref).

#define F_DIM 512
#define BM    128      // rows per block
#define BK    32       // k per LDS tile
#define NTMAX 8        // 16-col MFMA tiles per pass (128 cols)
#define KPAD  40       // padded leading dim in shorts (80 B rows: 16B-aligned, spreads banks)
#define TAU   1e-3f

typedef float f32x4  __attribute__((ext_vector_type(4)));
typedef short bf16x8 __attribute__((ext_vector_type(8)));
typedef unsigned short u16x4 __attribute__((ext_vector_type(4)));

__device__ inline unsigned short bf16_rne(float v) {
    unsigned u = __float_as_uint(v);
    u += 0x7FFFu + ((u >> 16) & 1u);
    return (unsigned short)(u >> 16);
}
__device__ inline float bf16_to_f32(unsigned short h) {
    return __uint_as_float(((unsigned)h) << 16);
}

__device__ __attribute__((noinline)) bool exact_pred(const float* __restrict__ xr,
                                                     const float* __restrict__ wr,
                                                     float bv) {
    double s0 = 0.0, s1 = 0.0, s2 = 0.0, s3 = 0.0;
    for (int k = 0; k < F_DIM; k += 4) {
        s0 = fma((double)xr[k + 0], (double)wr[k + 0], s0);
        s1 = fma((double)xr[k + 1], (double)wr[k + 1], s1);
        s2 = fma((double)xr[k + 2], (double)wr[k + 2], s2);
        s3 = fma((double)xr[k + 3], (double)wr[k + 3], s3);
    }
    double s = ((s0 + s1) + (s2 + s3)) + (double)bv;
    return s > 0.0;
}

__global__ __launch_bounds__(256, 3)
void ada_mfma(const float* __restrict__ x, const float* __restrict__ W,
              const float* __restrict__ bias, const float* __restrict__ alphas,
              float* __restrict__ out) {
    __shared__ unsigned short xs_hi[BM][KPAD], xs_lo[BM][KPAD];   // x tile, bf16 hi/lo
    __shared__ unsigned short wh[128][KPAD],  wl[128][KPAD];      // W tile (compacted cols)
    __shared__ int   se[272];     // compacted col -> original estimator
    __shared__ float st[272];     // trunc(alpha) (0 for pad)
    __shared__ float sb[272];     // bias
    __shared__ int   wcnt[4];

    const int tid = threadIdx.x;
    const int n0  = blockIdx.x * BM;

    // ---- compaction of active estimators (deterministic ballot prefix-sum)
    se[tid] = 0; st[tid] = 0.0f; sb[tid] = 0.0f;
    if (tid < 16) { se[256 + tid] = 0; st[256 + tid] = 0.0f; sb[256 + tid] = 0.0f; }
    __syncthreads();
    const float t = truncf(alphas[tid]);
    const bool flag = (t != 0.0f);
    const unsigned long long m64 = __ballot(flag);
    const int lane = tid & 63, wvi = tid >> 6;
    if (lane == 0) wcnt[wvi] = __popcll(m64);
    __syncthreads();
    int off = 0;
    #pragma unroll
    for (int w = 0; w < 4; ++w) if (w < wvi) off += wcnt[w];
    const int M = wcnt[0] + wcnt[1] + wcnt[2] + wcnt[3];
    if (flag) {
        const int slot = off + __popcll(m64 & ((1ull << lane) - 1ull));
        se[slot] = tid; st[slot] = t; sb[slot] = bias[tid];
    }
    __syncthreads();

    // ---- ids
    const int sr   = tid >> 3;          // staging row 0..31 (+i*32)
    const int sc   = (tid & 7) * 4;     // staging col (floats/shorts within k-tile)
    const int quad = (tid >> 4) & 3;    // lane>>4 within wave
    const int l15  = tid & 15;
    const int rw   = (tid >> 6) * 32;   // wave's row base within block

    const float* xp = x + (size_t)(n0 + sr) * F_DIM + sc;

    int part[2][4];
    #pragma unroll
    for (int mt = 0; mt < 2; ++mt)
        #pragma unroll
        for (int r = 0; r < 4; ++r) part[mt][r] = 0;

    for (int cb = 0; cb < M; cb += 128) {
        const int Mrem   = M - cb;
        const int NT     = (Mrem + 15) >> 4 < NTMAX ? (Mrem + 15) >> 4 : NTMAX;
        const int wstage = (NT + 1) >> 1;   // # of 32-row W staging groups

        const float* wp[4];
        #pragma unroll
        for (int i = 0; i < 4; ++i) {
            const int e = se[cb + sr + i * 32];
            wp[i] = W + (size_t)e * F_DIM + sc;
        }

        f32x4 acc[2][NTMAX];
        #pragma unroll
        for (int mt = 0; mt < 2; ++mt)
            #pragma unroll
            for (int nt = 0; nt < NTMAX; ++nt)
                acc[mt][nt] = (f32x4){0.0f, 0.0f, 0.0f, 0.0f};

        for (int k0 = 0; k0 < F_DIM; k0 += BK) {
            float4 xv[4], wvv[4];
            #pragma unroll
            for (int i = 0; i < 4; ++i)
                xv[i] = *(const float4*)(xp + (size_t)i * 32 * F_DIM + k0);
            #pragma unroll
            for (int i = 0; i < 4; ++i)
                if (i < wstage) wvv[i] = *(const float4*)(wp[i] + k0);

            __syncthreads();   // previous iteration's frag reads done

            #pragma unroll
            for (int i = 0; i < 4; ++i) {
                const int r = sr + i * 32;
                const float vv[4] = {xv[i].x, xv[i].y, xv[i].z, xv[i].w};
                u16x4 hv, lv;
                #pragma unroll
                for (int j = 0; j < 4; ++j) {
                    const unsigned short h = bf16_rne(vv[j]);
                    hv[j] = h;
                    lv[j] = bf16_rne(vv[j] - bf16_to_f32(h));
                }
                *(u16x4*)&xs_hi[r][sc] = hv;
                *(u16x4*)&xs_lo[r][sc] = lv;
            }
            #pragma unroll
            for (int i = 0; i < 4; ++i) {
                if (i < wstage) {
                    const int r = sr + i * 32;
                    const float vv[4] = {wvv[i].x, wvv[i].y, wvv[i].z, wvv[i].w};
                    u16x4 hv, lv;
                    #pragma unroll
                    for (int j = 0; j < 4; ++j) {
                        const unsigned short h = bf16_rne(vv[j]);
                        hv[j] = h;
                        lv[j] = bf16_rne(vv[j] - bf16_to_f32(h));
                    }
                    *(u16x4*)&wh[r][sc] = hv;
                    *(u16x4*)&wl[r][sc] = lv;
                }
            }

            __syncthreads();   // tiles visible

            bf16x8 ah[2], al[2];
            #pragma unroll
            for (int mt = 0; mt < 2; ++mt) {
                ah[mt] = *(const bf16x8*)&xs_hi[rw + mt * 16 + l15][quad * 8];
                al[mt] = *(const bf16x8*)&xs_lo[rw + mt * 16 + l15][quad * 8];
            }
            #pragma unroll
            for (int nt = 0; nt < NTMAX; ++nt) {
                if (nt < NT) {
                    const bf16x8 bh = *(const bf16x8*)&wh[nt * 16 + l15][quad * 8];
                    const bf16x8 bl = *(const bf16x8*)&wl[nt * 16 + l15][quad * 8];
                    #pragma unroll
                    for (int mt = 0; mt < 2; ++mt) {
                        acc[mt][nt] = __builtin_amdgcn_mfma_f32_16x16x32_bf16(ah[mt], bh, acc[mt][nt], 0, 0, 0);
                        acc[mt][nt] = __builtin_amdgcn_mfma_f32_16x16x32_bf16(al[mt], bh, acc[mt][nt], 0, 0, 0);
                        acc[mt][nt] = __builtin_amdgcn_mfma_f32_16x16x32_bf16(ah[mt], bl, acc[mt][nt], 0, 0, 0);
                    }
                }
            }
        }

        // ---- epilogue for this col pass: threshold + integer vote (C/D: col=l15, row=quad*4+reg)
        #pragma unroll
        for (int nt = 0; nt < NTMAX; ++nt) {
            if (nt < NT) {
                const int col = cb + nt * 16 + l15;
                const float tv = st[col];
                if (tv != 0.0f) {
                    const float bv = sb[col];
                    const int it = (int)tv;
                    #pragma unroll
                    for (int mt = 0; mt < 2; ++mt) {
                        #pragma unroll
                        for (int r = 0; r < 4; ++r) {
                            const float logit = acc[mt][nt][r] + bv;
                            bool pred = (logit > 0.0f);
                            if (fabsf(logit) < TAU) {
                                const int row = rw + mt * 16 + quad * 4 + r;
                                pred = exact_pred(x + (size_t)(n0 + row) * F_DIM,
                                                  W + (size_t)se[col] * F_DIM, bv);
                            }
                            if (pred) part[mt][r] += it;
                        }
                    }
                }
            }
        }
    }

    // ---- reduce the 16 col-lanes of each quad, then store 4 consecutive rows as float4
    #pragma unroll
    for (int mt = 0; mt < 2; ++mt) {
        #pragma unroll
        for (int r = 0; r < 4; ++r) {
            int v = part[mt][r];
            v += __shfl_xor(v, 1);
            v += __shfl_xor(v, 2);
            v += __shfl_xor(v, 4);
            v += __shfl_xor(v, 8);
            part[mt][r] = v;
        }
    }
    if (l15 == 0) {
        #pragma unroll
        for (int mt = 0; mt < 2; ++mt) {
            float4 o;
            o.x = (part[mt][0] > 0) ? 1.0f : (part[mt][0] < 0 ? -1.0f : 0.0f);
            o.y = (part[mt][1] > 0) ? 1.0f : (part[mt][1] < 0 ? -1.0f : 0.0f);
            o.z = (part[mt][2] > 0) ? 1.0f : (part[mt][2] < 0 ? -1.0f : 0.0f);
            o.w = (part[mt][3] > 0) ? 1.0f : (part[mt][3] < 0 ? -1.0f : 0.0f);
            *(float4*)(out + n0 + rw + mt * 16 + quad * 4) = o;
        }
    }
}

extern "C" void kernel_launch(void* const* d_in, const int* in_sizes, int n_in,
                              void* d_out, int out_size, void* d_ws, size_t ws_size,
                              hipStream_t stream) {
    const float* x      = (const float*)d_in[0];   // [N, 512]
    const float* W      = (const float*)d_in[1];   // [256, 512]
    const float* bias   = (const float*)d_in[2];   // [256]
    const float* alphas = (const float*)d_in[3];   // [256]
    float* out = (float*)d_out;                    // [N]

    const int n = in_sizes[0] / F_DIM;             // 131072
    const int nblocks = n / BM;                    // 1024

    ada_mfma<<<dim3(nblocks), dim3(256), 0, stream>>>(x, W, bias, alphas, out);
}